// Round 1
// baseline (164.182 us; speedup 1.0000x reference)
//
#include <hip/hip_runtime.h>

// Problem constants (from reference setup_inputs)
#define E_TOT 1000000
#define D_DIM 128
#define C_CAP 262144
#define N_IDS 16384

// Counting-sort geometry over C slots
#define TK 4096      // threads covering C
#define RK 64        // slots per thread: TK*RK == C_CAP
#define NB 102       // buckets: [key<0], keys 0..99, [key>=100]

// Miss-rank geometry over E rows
#define TM 16384     // threads covering E
#define RM 62        // rows per thread: TM*RM >= E_TOT

static_assert(TK * RK == C_CAP, "geometry");
static_assert((long)TM * RM >= E_TOT, "geometry");

// ---------------------------------------------------------------------------
// K1: scatter batch presence: protected slots (hits) + miss flags (per row)
__global__ void scatter_kernel(const int* __restrict__ ids,
                               const int* __restrict__ idx_map,
                               const int* __restrict__ inv,
                               unsigned char* __restrict__ prot,
                               unsigned char* __restrict__ missFlag) {
    int i = blockIdx.x * blockDim.x + threadIdx.x;
    if (i >= N_IDS) return;
    int id = ids[i];
    if (id < 0 || id >= E_TOT) return;
    int row = idx_map[id];
    if (row < 0 || row >= E_TOT) return;
    int s = inv[row];
    if (s >= 0) {
        if (s < C_CAP) prot[s] = 1;
    } else {
        missFlag[row] = 1;
    }
}

// ---------------------------------------------------------------------------
// K2: per-thread per-bucket counts over C slots (stable counting sort pass A)
__device__ __forceinline__ int bucket_of(int crow,
                                         const int* __restrict__ freq) {
    int key = (crow < 0) ? -1 : freq[crow < E_TOT ? crow : (E_TOT - 1)];
    return (key < 0) ? 0 : (key >= 100 ? 101 : key + 1);
}

__global__ void key_count_kernel(const unsigned char* __restrict__ prot,
                                 const int* __restrict__ cidx,
                                 const int* __restrict__ freq,
                                 int* __restrict__ counts) {
    int t = blockIdx.x * blockDim.x + threadIdx.x; // < TK
    int base = t * RK;
    for (int k = 0; k < RK; ++k) {
        int s = base + k;
        if (prot[s]) continue;
        int b = bucket_of(cidx[s], freq);
        counts[b * TK + t] += 1;   // private column, no atomics needed
    }
}

// ---------------------------------------------------------------------------
// K3: per-bucket exclusive scan across TK thread-columns (pass B)
__global__ void key_scan_kernel(int* __restrict__ counts,
                                int* __restrict__ bucketTotal) {
    int b = blockIdx.x;      // bucket
    int t = threadIdx.x;     // 0..255
    int* base = counts + b * TK;
    int v[16], loc[16];
    int run = 0;
#pragma unroll
    for (int k = 0; k < 16; ++k) {
        v[k] = base[t * 16 + k];
        loc[k] = run;
        run += v[k];
    }
    __shared__ int sh[256];
    sh[t] = run;
    __syncthreads();
    for (int o = 1; o < 256; o <<= 1) {
        int x = 0;
        if (t >= o) x = sh[t - o];
        __syncthreads();
        if (t >= o) sh[t] += x;
        __syncthreads();
    }
    int excl = sh[t] - run;
#pragma unroll
    for (int k = 0; k < 16; ++k) base[t * 16 + k] = excl + loc[k];
    if (t == 255) bucketTotal[b] = sh[255];
}

// K4: tiny exclusive scan of bucket totals
__global__ void bucket_start_kernel(const int* __restrict__ bucketTotal,
                                    int* __restrict__ bucketStart) {
    if (threadIdx.x == 0 && blockIdx.x == 0) {
        int run = 0;
        for (int b = 0; b < NB; ++b) {
            bucketStart[b] = run;
            run += bucketTotal[b];
        }
    }
}

// ---------------------------------------------------------------------------
// K5: replay — place each unprotected slot at its stable order position
__global__ void key_place_kernel(const unsigned char* __restrict__ prot,
                                 const int* __restrict__ cidx,
                                 const int* __restrict__ freq,
                                 int* __restrict__ counts,
                                 const int* __restrict__ bucketStart,
                                 int* __restrict__ order) {
    int t = blockIdx.x * blockDim.x + threadIdx.x; // < TK
    int base = t * RK;
    for (int k = 0; k < RK; ++k) {
        int s = base + k;
        if (prot[s]) continue;
        int b = bucket_of(cidx[s], freq);
        int off = counts[b * TK + t];
        counts[b * TK + t] = off + 1;
        int pos = bucketStart[b] + off;
        if (pos >= 0 && pos < C_CAP) order[pos] = s;
    }
}

// ---------------------------------------------------------------------------
// K6: per-thread miss counts over E rows
__global__ void miss_count_kernel(const unsigned char* __restrict__ missFlag,
                                  int* __restrict__ missCnt) {
    int t = blockIdx.x * blockDim.x + threadIdx.x; // < TM
    int base = t * RM;
    int c = 0;
    for (int k = 0; k < RM; ++k) {
        int r = base + k;
        if (r < E_TOT) c += missFlag[r];
    }
    missCnt[t] = c;
}

// K7: single-block scan of TM=16384 counts (in place -> exclusive prefix)
__global__ void miss_scan_kernel(int* __restrict__ missCnt) {
    int t = threadIdx.x; // 0..1023
    int v[16], loc[16];
    int run = 0;
#pragma unroll
    for (int k = 0; k < 16; ++k) {
        v[k] = missCnt[t * 16 + k];
        loc[k] = run;
        run += v[k];
    }
    __shared__ int sh[1024];
    sh[t] = run;
    __syncthreads();
    for (int o = 1; o < 1024; o <<= 1) {
        int x = 0;
        if (t >= o) x = sh[t - o];
        __syncthreads();
        if (t >= o) sh[t] += x;
        __syncthreads();
    }
    int excl = sh[t] - run;
#pragma unroll
    for (int k = 0; k < 16; ++k) missCnt[t * 16 + k] = excl + loc[k];
}

// K8: replay — write rank (index among distinct misses in ascending row order)
__global__ void miss_rank_kernel(const unsigned char* __restrict__ missFlag,
                                 const int* __restrict__ missCnt,
                                 int* __restrict__ missRank) {
    int t = blockIdx.x * blockDim.x + threadIdx.x; // < TM
    int base = t * RM;
    int rank = missCnt[t];
    for (int k = 0; k < RM; ++k) {
        int r = base + k;
        if (r < E_TOT && missFlag[r]) {
            missRank[r] = rank++;
        }
    }
}

// ---------------------------------------------------------------------------
// K9: final — slot translation + row gather.
// d_out[0:N)          = (float)gpu_row_idxs
// d_out[N : N + N*D)  = gathered f32 rows
__global__ void final_kernel(const int* __restrict__ ids,
                             const int* __restrict__ idx_map,
                             const int* __restrict__ inv,
                             const int* __restrict__ missRank,
                             const int* __restrict__ order,
                             const float* __restrict__ weight,
                             const float* __restrict__ cuda_weight,
                             float* __restrict__ out) {
    int i = blockIdx.x * 4 + (threadIdx.x >> 6);
    int lane = threadIdx.x & 63;
    if (i >= N_IDS) return;
    int id = ids[i];
    int row = (id >= 0 && id < E_TOT) ? idx_map[id] : 0;
    if (row < 0) row = 0;
    if (row >= E_TOT) row = E_TOT - 1;
    int s0 = inv[row];
    int slot;
    const float* src;
    if (s0 >= 0) {
        slot = s0;
        src = cuda_weight + (size_t)slot * D_DIM;
    } else {
        int r = missRank[row];
        if (r < 0) r = 0;
        if (r >= C_CAP) r = C_CAP - 1;
        slot = order[r];
        src = weight + (size_t)row * D_DIM;
    }
    if (lane == 0) out[i] = (float)slot;
    const float2* s2 = (const float2*)src;
    float2* d2 = (float2*)(out + N_IDS + (size_t)i * D_DIM);
    d2[lane] = s2[lane];   // 64 lanes x float2 = 128 floats
}

// ---------------------------------------------------------------------------
extern "C" void kernel_launch(void* const* d_in, const int* in_sizes, int n_in,
                              void* d_out, int out_size, void* d_ws, size_t ws_size,
                              hipStream_t stream) {
    const int* ids   = (const int*)d_in[0];
    const int* idx_map = (const int*)d_in[1];
    const int* cidx  = (const int*)d_in[2];  // cached_idx_map
    const int* inv   = (const int*)d_in[3];  // inverted_cached_idx
    const int* freq  = (const int*)d_in[4];  // freq_cnter
    const float* weight      = (const float*)d_in[5];
    const float* cuda_weight = (const float*)d_in[6];
    float* out = (float*)d_out;

    // Workspace layout (256B aligned chunks)
    unsigned char* ws = (unsigned char*)d_ws;
    size_t o = 0;
    auto take = [&](size_t bytes) {
        size_t r = o;
        o += (bytes + 255) & ~(size_t)255;
        return r;
    };
    unsigned char* prot     = ws + take(C_CAP);                 // C bytes
    unsigned char* missFlag = ws + take(E_TOT);                 // E bytes
    int* counts      = (int*)(ws + take((size_t)NB * TK * 4));  // 1.67 MB
    int* bucketTotal = (int*)(ws + take(NB * 4));
    int* bucketStart = (int*)(ws + take(NB * 4));
    int* order       = (int*)(ws + take((size_t)C_CAP * 4));    // 1 MB
    int* missCnt     = (int*)(ws + take((size_t)TM * 4));
    int* missRank    = (int*)(ws + take((size_t)E_TOT * 4));    // 4 MB
    (void)ws_size; (void)in_sizes; (void)n_in; (void)out_size;

    // Zero the accumulation regions (every call; ws is poisoned once)
    hipMemsetAsync(prot, 0, C_CAP, stream);
    hipMemsetAsync(missFlag, 0, E_TOT, stream);
    hipMemsetAsync(counts, 0, (size_t)NB * TK * 4, stream);

    scatter_kernel<<<N_IDS / 256, 256, 0, stream>>>(ids, idx_map, inv, prot, missFlag);

    key_count_kernel<<<TK / 256, 256, 0, stream>>>(prot, cidx, freq, counts);
    key_scan_kernel<<<NB, 256, 0, stream>>>(counts, bucketTotal);
    bucket_start_kernel<<<1, 64, 0, stream>>>(bucketTotal, bucketStart);
    key_place_kernel<<<TK / 256, 256, 0, stream>>>(prot, cidx, freq, counts,
                                                   bucketStart, order);

    miss_count_kernel<<<TM / 256, 256, 0, stream>>>(missFlag, missCnt);
    miss_scan_kernel<<<1, 1024, 0, stream>>>(missCnt);
    miss_rank_kernel<<<TM / 256, 256, 0, stream>>>(missFlag, missCnt, missRank);

    final_kernel<<<N_IDS / 4, 256, 0, stream>>>(ids, idx_map, inv, missRank, order,
                                                weight, cuda_weight, out);
}

// Round 2
// 116.902 us; speedup vs baseline: 1.4044x; 1.4044x over previous
//
#include <hip/hip_runtime.h>

// Problem constants (from reference setup_inputs)
#define E_TOT 1000000
#define D_DIM 128
#define C_CAP 262144
#define N_IDS 16384

// Counting-sort geometry over C slots
#define TK 4096      // thread-columns covering C
#define RK 64        // slots per thread: TK*RK == C_CAP
#define NB 102       // buckets: [key<0], keys 0..99, [key>=100]
#define NW 31250     // miss bit words: E/32

static_assert(TK * RK == C_CAP, "geometry");
static_assert(NW * 32 == E_TOT, "geometry");

// ---------------------------------------------------------------------------
// D2: scatter batch presence into bitmasks (atomicOr = idempotent/deterministic)
__global__ void scatter_kernel(const int* __restrict__ ids,
                               const int* __restrict__ idx_map,
                               const int* __restrict__ inv,
                               unsigned int* __restrict__ protBits,
                               unsigned int* __restrict__ missBits) {
    int i = blockIdx.x * 256 + threadIdx.x;
    if (i >= N_IDS) return;
    int id = ids[i];
    if (id < 0 || id >= E_TOT) return;
    int row = idx_map[id];
    if (row < 0 || row >= E_TOT) return;
    int s = inv[row];
    if (s >= 0) {
        if (s < C_CAP) atomicOr(&protBits[s >> 5], 1u << (s & 31));
    } else {
        atomicOr(&missBits[row >> 5], 1u << (row & 31));
    }
}

// ---------------------------------------------------------------------------
// D3: blocks 0..15  -> key histogram over C slots (per-thread column counts,
//                      stable counting-sort pass A) + bucketArr cache
//     block 16      -> exclusive word-prefix scan over missBits popcounts
__global__ void count_kernel(const unsigned int* __restrict__ protBits,
                             const int* __restrict__ cidx,
                             const int* __restrict__ freq,
                             int* __restrict__ counts,
                             unsigned char* __restrict__ bucketArr,
                             const unsigned int* __restrict__ missBits,
                             int* __restrict__ wordPrefix,
                             int* __restrict__ missTotal) {
    __shared__ int sh[256];
    if (blockIdx.x < 16) {
        int t = blockIdx.x * 256 + threadIdx.x; // < TK
        int base = t * RK;
        for (int k = 0; k < RK; ++k) {
            int s = base + k;
            int b;
            if ((protBits[s >> 5] >> (s & 31)) & 1u) {
                b = 255; // protected: never evictable
            } else {
                int crow = cidx[s];
                int key;
                if (crow < 0) key = -1;
                else key = freq[crow < E_TOT ? crow : (E_TOT - 1)];
                b = (key < 0) ? 0 : (key >= 100 ? 101 : key + 1);
                counts[b * TK + t] += 1; // private column (pre-zeroed)
            }
            bucketArr[s] = (unsigned char)b;
        }
    } else {
        // single block: word-granular exclusive prefix of miss popcounts
        int t = threadIdx.x;
        const int WPT = (NW + 255) / 256; // 123
        int w0 = t * WPT;
        int sum = 0;
        for (int k = 0; k < WPT; ++k) {
            int w = w0 + k;
            if (w < NW) sum += __popc(missBits[w]);
        }
        sh[t] = sum;
        __syncthreads();
        for (int o = 1; o < 256; o <<= 1) {
            int x = 0;
            if (t >= o) x = sh[t - o];
            __syncthreads();
            if (t >= o) sh[t] += x;
            __syncthreads();
        }
        int run = sh[t] - sum; // exclusive base for this thread
        for (int k = 0; k < WPT; ++k) {
            int w = w0 + k;
            if (w < NW) {
                wordPrefix[w] = run;
                run += __popc(missBits[w]);
            }
        }
        if (t == 255) *missTotal = sh[255];
    }
}

// ---------------------------------------------------------------------------
// D4: per-bucket exclusive scan across TK thread-columns (pass B)
__global__ void key_scan_kernel(int* __restrict__ counts,
                                int* __restrict__ bucketTotal) {
    int b = blockIdx.x;  // bucket
    int t = threadIdx.x; // 0..255
    int* base = counts + b * TK;
    int loc[16];
    int run = 0;
#pragma unroll
    for (int k = 0; k < 16; ++k) {
        int v = base[t * 16 + k];
        loc[k] = run;
        run += v;
    }
    __shared__ int sh[256];
    sh[t] = run;
    __syncthreads();
    for (int o = 1; o < 256; o <<= 1) {
        int x = 0;
        if (t >= o) x = sh[t - o];
        __syncthreads();
        if (t >= o) sh[t] += x;
        __syncthreads();
    }
    int excl = sh[t] - run;
#pragma unroll
    for (int k = 0; k < 16; ++k) base[t * 16 + k] = excl + loc[k];
    if (t == 255) bucketTotal[b] = sh[255];
}

// ---------------------------------------------------------------------------
// D5: replay — place each unprotected slot at its stable order position.
// Only positions < missTotal are ever consumed; skip everything else.
__global__ void place_kernel(const unsigned char* __restrict__ bucketArr,
                             int* __restrict__ counts,
                             const int* __restrict__ bucketTotal,
                             const int* __restrict__ missTotal,
                             int* __restrict__ order) {
    __shared__ int bstart[NB];
    __shared__ int shm;
    if (threadIdx.x == 0) {
        int run = 0;
        for (int b = 0; b < NB; ++b) {
            bstart[b] = run;
            run += bucketTotal[b];
        }
        shm = *missTotal;
    }
    __syncthreads();
    int m = shm;
    int t = blockIdx.x * 256 + threadIdx.x; // < TK
    int base = t * RK;
    for (int k = 0; k < RK; ++k) {
        int s = base + k;
        int b = bucketArr[s];
        if (b == 255) continue;
        int bs = bstart[b];
        if (bs >= m) continue; // whole bucket beyond consumed range
        int off = counts[b * TK + t];
        int pos = bs + off;
        if (pos < m) {
            counts[b * TK + t] = off + 1;
            order[pos] = s;
        }
    }
}

// ---------------------------------------------------------------------------
// D6: final — slot translation + row gather.
// d_out[0:N)          = (float)gpu_row_idxs
// d_out[N : N + N*D)  = gathered f32 rows
__global__ void final_kernel(const int* __restrict__ ids,
                             const int* __restrict__ idx_map,
                             const int* __restrict__ inv,
                             const unsigned int* __restrict__ missBits,
                             const int* __restrict__ wordPrefix,
                             const int* __restrict__ order,
                             const float* __restrict__ weight,
                             const float* __restrict__ cuda_weight,
                             float* __restrict__ out) {
    int i = blockIdx.x * 4 + (threadIdx.x >> 6);
    int lane = threadIdx.x & 63;
    if (i >= N_IDS) return;
    int id = ids[i];
    int row = (id >= 0 && id < E_TOT) ? idx_map[id] : 0;
    if (row < 0) row = 0;
    if (row >= E_TOT) row = E_TOT - 1;
    int s0 = inv[row];
    int slot;
    const float* src;
    if (s0 >= 0) {
        slot = s0;
        src = cuda_weight + (size_t)slot * D_DIM;
    } else {
        unsigned int w = (unsigned)row >> 5;
        unsigned int mask = (1u << (row & 31)) - 1u;
        int rank = wordPrefix[w] + __popc(missBits[w] & mask);
        if (rank < 0) rank = 0;
        if (rank >= C_CAP) rank = C_CAP - 1;
        slot = order[rank];
        src = weight + (size_t)row * D_DIM;
    }
    if (lane == 0) out[i] = (float)slot;
    const float2* s2 = (const float2*)src;
    float2* d2 = (float2*)(out + N_IDS + (size_t)i * D_DIM);
    d2[lane] = s2[lane]; // 64 lanes x float2 = 128 floats
}

// ---------------------------------------------------------------------------
extern "C" void kernel_launch(void* const* d_in, const int* in_sizes, int n_in,
                              void* d_out, int out_size, void* d_ws, size_t ws_size,
                              hipStream_t stream) {
    const int* ids     = (const int*)d_in[0];
    const int* idx_map = (const int*)d_in[1];
    const int* cidx    = (const int*)d_in[2]; // cached_idx_map
    const int* inv     = (const int*)d_in[3]; // inverted_cached_idx
    const int* freq    = (const int*)d_in[4]; // freq_cnter
    const float* weight      = (const float*)d_in[5];
    const float* cuda_weight = (const float*)d_in[6];
    float* out = (float*)d_out;

    // Workspace layout. Zeroed region FIRST (one contiguous memset).
    unsigned char* ws = (unsigned char*)d_ws;
    size_t o = 0;
    auto take = [&](size_t bytes) {
        size_t r = o;
        o += (bytes + 255) & ~(size_t)255;
        return r;
    };
    int* counts            = (int*)(ws + take((size_t)NB * TK * 4)); // 1.67 MB
    unsigned int* protBits = (unsigned int*)(ws + take(C_CAP / 8)); // 32 KB
    unsigned int* missBits = (unsigned int*)(ws + take((size_t)NW * 4)); // 125 KB
    size_t zbytes = o; // contiguous zero region
    unsigned char* bucketArr = ws + take(C_CAP);                    // 256 KB
    int* wordPrefix  = (int*)(ws + take((size_t)NW * 4));           // 125 KB
    int* missTotal   = (int*)(ws + take(4));
    int* bucketTotal = (int*)(ws + take(NB * 4));
    int* order       = (int*)(ws + take((size_t)C_CAP * 4));        // 1 MB
    (void)ws_size; (void)in_sizes; (void)n_in; (void)out_size;

    // D1: single fill for all accumulation state
    hipMemsetAsync(ws, 0, zbytes, stream);

    // D2: presence scatter
    scatter_kernel<<<N_IDS / 256, 256, 0, stream>>>(ids, idx_map, inv,
                                                    protBits, missBits);

    // D3: key histogram (blocks 0-15) + miss word-prefix scan (block 16)
    count_kernel<<<17, 256, 0, stream>>>(protBits, cidx, freq, counts,
                                         bucketArr, missBits, wordPrefix,
                                         missTotal);

    // D4: per-bucket stable scan
    key_scan_kernel<<<NB, 256, 0, stream>>>(counts, bucketTotal);

    // D5: place evictable slots into order[0..missTotal)
    place_kernel<<<TK / 256, 256, 0, stream>>>(bucketArr, counts, bucketTotal,
                                               missTotal, order);

    // D6: translation + gather
    final_kernel<<<N_IDS / 4, 256, 0, stream>>>(ids, idx_map, inv, missBits,
                                                wordPrefix, order, weight,
                                                cuda_weight, out);
}